// Round 11
// baseline (161.611 us; speedup 1.0000x reference)
//
#include <hip/hip_runtime.h>
#include <hip/hip_bf16.h>
#include <cstdint>
#include <cstddef>

#define EMB_K   1024
#define EMB_C   256
#define HWB     4096        // 64*64 per batch
#define NPIX    65536       // 16*4096

typedef __bf16 bf16x8 __attribute__((ext_vector_type(8)));
typedef float  f32x4  __attribute__((ext_vector_type(4)));

__device__ __forceinline__ unsigned short bf16bits(float v) {
  __hip_bfloat16 h = __float2bfloat16(v);
  return __builtin_bit_cast(unsigned short, h);
}

// ---- emb -> bf16 row-major + fp32 norms; zero loss + ctr ----
__global__ void k_emb(const float* __restrict__ emb, unsigned short* __restrict__ emb_bf,
                      float* __restrict__ enorm, float* __restrict__ loss,
                      unsigned* __restrict__ ctr) {
  int k = blockIdx.x;      // 0..1023
  int c = threadIdx.x;     // 0..255
  if (k == 0 && c == 0) { *loss = 0.f; *ctr = 0u; }
  float v = emb[(size_t)k * EMB_C + c];
  emb_bf[(size_t)k * EMB_C + c] = bf16bits(v);
  float s = v * v;
  for (int m = 32; m; m >>= 1) s += __shfl_down(s, m, 64);
  __shared__ float red[4];
  int lane = c & 63, w = c >> 6;
  if (lane == 0) red[w] = s;
  __syncthreads();
  if (c == 0) enorm[k] = red[0] + red[1] + red[2] + red[3];
}

// ---- staging: 64 rows x 256c bf16 = 32KB, XOR-swizzled 16B chunks, glds ----
// 512-thread: 2048 chunks, 4 per thread (4 vmcnt units per stage)
__device__ __forceinline__ void stage64(const unsigned short* __restrict__ rows,
                                        unsigned char* buf, int t) {
#pragma unroll
  for (int j = 0; j < 4; ++j) {
    int d = j * 512 + t;             // linear dest chunk 0..2047
    int r = d >> 5;                  // row 0..63
    int slot = d & 31;
    int c16 = ((slot >> 3) << 3) | ((slot & 7) ^ (r & 7));
    const unsigned short* src = rows + (size_t)r * EMB_C + c16 * 8;
    __builtin_amdgcn_global_load_lds(
        (const __attribute__((address_space(1))) void*)src,
        (__attribute__((address_space(3))) void*)(buf + (unsigned)(j * 8192 + (t >> 6) * 1024)),
        16, 0, 0);
  }
}

// ================= fused main kernel =================
// 256 blocks x 512 thr, 1 block/CU. Block owns 256 n (one b), all 1024 k.
// Wave w owns n-rows [32w,32w+32) and ALL k (af[2][8]; no af sharing between
// waves) -> af loads DIRECT from x to registers: 128 scalar loads/thread,
// 16-lane groups read full 64B lines. NO A-LDS tile, NO prologue barriers,
// NO xn atomics (shfl_xor over quads). R8/R9/R10 proved the k-loop structure
// is off the critical path; this round deletes the prologue round-trip that
// R10's counters (2.9M bank conflicts, 55us of non-kloop time) indict.
// K-loop: 4-buf rotation, depth-3 stage issued AFTER barrier(kt) (overwrites
// buf[(kt-1)&3], free since all waves passed barrier(kt) => compute(kt-1)
// done); wait vmcnt(8) = stage issued 3 tiles ago. Epilogue: 2 passes of
// 128c x 256n (128KB tile), 4-thr/n gathers = full 64B lines, rotate-by-3
// aligned f32x4 stores.
// LDS: [0,128K) bufs 4x32KB | cjl 4K | keys 1K | xn 1K | red
#define LDS_BYTES 137280

__global__ __launch_bounds__(512) void
k_main(const float* __restrict__ x, const float* __restrict__ emb,
       const unsigned short* __restrict__ embbf, const float* __restrict__ enorm,
       float* __restrict__ out, float* __restrict__ loss, unsigned* __restrict__ ctr) {
  extern __shared__ char smem[];
  float*    cjl    = (float*)(smem + 131072);          // 1024 f32
  unsigned* keys_l = (unsigned*)(smem + 135168);       // 256 u32
  float*    xn_l   = (float*)(smem + 136192);          // 256 f32
  float*    red    = (float*)(smem + 137216);          // 16 f32

  int n0 = blockIdx.x * 256;
  int b  = n0 >> 12, hw0 = n0 & 4095;
  int t = threadIdx.x, w = t >> 6, lane = t & 63;
  int quad = lane >> 4, lr = lane & 15;

  // B(0..2) staged immediately: hides under the whole prologue
  stage64(embbf,                (unsigned char*)smem,          t);
  stage64(embbf + 64 * EMB_C,   (unsigned char*)smem + 32768,  t);
  stage64(embbf + 128 * EMB_C,  (unsigned char*)smem + 65536,  t);

  for (int i = t; i < 1024; i += 512) cjl[i] = 0.375f - 0.5f * enorm[i];

  // ---- prologue: af DIRECT from x (no LDS, no barriers) ----
  // af[i][s] elem j  <->  x[c = s*32+quad*8+j][hw0 + rA], rA = w*32+i*16+lr.
  // Per (i,s,j) instr: 16 lr-lanes read 64B contiguous (aligned), 4 quads = 4
  // full lines. 16 loads in flight per pair-group for latency depth.
  bf16x8 af[2][8];
  float xn2[2];
  const float* xb = x + (size_t)b * (EMB_C * HWB) + hw0;
#pragma unroll
  for (int i = 0; i < 2; ++i) {
    int rA = w * 32 + i * 16 + lr;
    float xs = 0.f;
#pragma unroll
    for (int s2 = 0; s2 < 4; ++s2) {       // pairs of s-fragments
      float v[2][8];
#pragma unroll
      for (int h = 0; h < 2; ++h)
#pragma unroll
        for (int j = 0; j < 8; ++j)
          v[h][j] = xb[(size_t)((s2 * 2 + h) * 32 + quad * 8 + j) * HWB + rA];
#pragma unroll
      for (int h = 0; h < 2; ++h) {
        union { unsigned u[4]; bf16x8 f; } pk;
#pragma unroll
        for (int m = 0; m < 4; ++m) {
          xs += v[h][2 * m] * v[h][2 * m] + v[h][2 * m + 1] * v[h][2 * m + 1];
          pk.u[m] = (unsigned)bf16bits(v[h][2 * m]) |
                    ((unsigned)bf16bits(v[h][2 * m + 1]) << 16);
        }
        af[i][s2 * 2 + h] = pk.f;
      }
    }
    xn2[i] = xs;
  }
#pragma unroll
  for (int i = 0; i < 2; ++i) {            // sum over the 4 quads (c-quarters)
    xn2[i] += __shfl_xor(xn2[i], 16, 64);
    xn2[i] += __shfl_xor(xn2[i], 32, 64);
  }
  if (quad == 0) { xn_l[w * 32 + lr] = xn2[0]; xn_l[w * 32 + 16 + lr] = xn2[1]; }
  __syncthreads();   // cjl/xn_l visible; stages 0-2 landed (vmcnt drained)

  // ---- K-loop: 16 tiles of 64 k; 4-buf, depth-3 stage, 1 barrier/tile ----
  unsigned best[2][4] = {};
  for (int kt = 0; kt < 16; ++kt) {
    // wait own stage(kt): outstanding = stages kt..kt+2 (12 chunks) steady
    if (kt < 14)       asm volatile("s_waitcnt vmcnt(8)" ::: "memory");
    else if (kt == 14) asm volatile("s_waitcnt vmcnt(4)" ::: "memory");
    else               asm volatile("s_waitcnt vmcnt(0)" ::: "memory");
    __builtin_amdgcn_s_barrier();          // all waves' stage(kt) landed;
                                           // all waves done compute(kt-1)
    __builtin_amdgcn_sched_barrier(0);     // no hoist above the barrier
    if (kt < 13)                           // overwrites buf[(kt-1)&3]: free
      stage64(embbf + (size_t)(kt + 3) * 64 * EMB_C,
              (unsigned char*)smem + (((kt + 3) & 3) << 15), t);
    const unsigned char* srcB = (const unsigned char*)smem + ((kt & 3) << 15);
    float cj[4]; unsigned kp[4];
#pragma unroll
    for (int j = 0; j < 4; ++j) {
      int k = kt * 64 + j * 16 + lr;
      cj[j] = cjl[k];
      kp[j] = 1023u - (unsigned)k;
    }
    f32x4 acc[2][4] = {};
#pragma unroll
    for (int s = 0; s < 8; ++s) {
      int cc = s * 4 + quad;
      int pos = ((cc >> 3) << 3) | ((cc & 7) ^ (lr & 7));   // rB&7 == lr&7
      bf16x8 bf[4];
#pragma unroll
      for (int j = 0; j < 4; ++j)
        bf[j] = *(const bf16x8*)(srcB + (j * 16 + lr) * 512 + pos * 16);
#pragma unroll
      for (int i = 0; i < 2; ++i)
#pragma unroll
        for (int j = 0; j < 4; ++j)
          acc[i][j] = __builtin_amdgcn_mfma_f32_16x16x32_bf16(af[i][s], bf[j], acc[i][j], 0, 0, 0);
    }
    // fold argmin keys: f = dot + 0.375 - 0.5||e||^2 in (0.04,0.71) -> positive
    // float u32-order-correct; low 10 mantissa bits carry (1023-k).
#pragma unroll
    for (int i = 0; i < 2; ++i)
#pragma unroll
      for (int j = 0; j < 4; ++j)
#pragma unroll
        for (int r = 0; r < 4; ++r) {
          float f = acc[i][j][r] + cj[j];
          unsigned key = (__float_as_uint(f) & 0xFFFFFC00u) | kp[j];
          best[i][r] = best[i][r] > key ? best[i][r] : key;
        }
  }

  // ---- combine keys across the 16 k-lanes; plain writes (rows unshared) ----
#pragma unroll
  for (int i = 0; i < 2; ++i)
#pragma unroll
    for (int r = 0; r < 4; ++r) {
      unsigned v = best[i][r];
#pragma unroll
      for (int m = 1; m < 16; m <<= 1) {
        unsigned o = (unsigned)__shfl_xor((int)v, m, 64);
        v = v > o ? v : o;
      }
      if (lr == 0) keys_l[w * 32 + i * 16 + quad * 4 + r] = v;
    }
  __syncthreads();

  // ---- loss partial: d2 = ||x||^2 + 0.75 - 2*f_hat ----
  if (t < 256) {
    unsigned key = keys_l[t];
    float fh = __uint_as_float(key & 0xFFFFFC00u);
    float lsum = xn_l[t] + 0.75f - 2.0f * fh;
    for (int m = 32; m; m >>= 1) lsum += __shfl_down(lsum, m, 64);
    if (lane == 0) red[w] = lsum;
  }
  __syncthreads();
  if (t == 0) {
    atomicAdd(loss, red[0] + red[1] + red[2] + red[3]);
    __threadfence();
  }

  // ---- output: 2 passes of 128c x 256n (128KB tile), rotate-by-3 stores ----
  // 4 thr/n: lanes(ch=0..3) read er+q*16+ch*4 -> 64B fully-used lines.
  float* tile = (float*)smem;
  int nn = t >> 2, ch = t & 3;               // nn 0..127
  int idxA = 1023 - (int)(keys_l[nn] & 1023u);
  int idxB = 1023 - (int)(keys_l[128 + nn] & 1023u);
  const float* erA = emb + (size_t)idxA * EMB_C;
  const float* erB = emb + (size_t)idxB * EMB_C;
  int nrotA = (nn - 3) & 255;
  int nrotB = (nn + 125) & 255;              // (nn+128-3)&255
  float* ob = out + 1 + (size_t)b * (EMB_C * HWB) + hw0;
  for (int p = 0; p < 2; ++p) {
    int c0 = p * 128;
    if (p) __syncthreads();                  // pass-0 stores done before rewrite
#pragma unroll
    for (int q = 0; q < 8; ++q) {            // L2-resident gathers
      f32x4 va = *(const f32x4*)(erA + c0 + q * 16 + ch * 4);
      f32x4 vb = *(const f32x4*)(erB + c0 + q * 16 + ch * 4);
#pragma unroll
      for (int m = 0; m < 4; ++m) {
        tile[(q * 16 + ch * 4 + m) * 256 + nrotA] = va[m];
        tile[(q * 16 + ch * 4 + m) * 256 + nrotB] = vb[m];
      }
    }
    __syncthreads();
#pragma unroll
    for (int cc = 0; cc < 16; ++cc) {        // wave w: c-rows w*16..w*16+15
      int cl = w * 16 + cc;
      const float* tr = tile + cl * 256;
      float* F = ob + (size_t)(c0 + cl) * HWB;
      if (lane < 63) {
        f32x4 q = *(const f32x4*)(tr + 4 * lane);    // aligned b128
        *(f32x4*)(F + 3 + 4 * lane) = q;             // aligned 16B store
      }
      if (lane == 0) { F[0] = tr[253]; F[1] = tr[254]; F[2] = tr[255]; }
      if (lane == 63) { F[255] = tr[252]; }
    }
  }

  // ---- fused finalize: last block writes out[0] ----
  if (t == 0) {
    unsigned done = atomicAdd(ctr, 1u);
    if (done == gridDim.x - 1) {
      float total = atomicAdd(loss, 0.f);   // device-scope read of final sum
      out[0] = 1.0625f * total / 16777216.0f;
    }
  }
}

extern "C" void kernel_launch(void* const* d_in, const int* in_sizes, int n_in,
                              void* d_out, int out_size, void* d_ws, size_t ws_size,
                              hipStream_t stream) {
  const float* x   = (const float*)d_in[0];   // [16,256,64,64]
  const float* emb = (const float*)d_in[1];   // [1024,256]
  float* out = (float*)d_out;                 // [1 + 16777216]
  char*  ws  = (char*)d_ws;

  unsigned short* emb_bf = (unsigned short*)ws;                 // 512 KB
  float*          enorm  = (float*)(ws + 524288);               // 4 KB
  float*          loss   = (float*)(ws + 528384);               // 4 B
  unsigned*       ctr    = (unsigned*)(ws + 528388);            // 4 B

  hipFuncSetAttribute((const void*)k_main,
                      hipFuncAttributeMaxDynamicSharedMemorySize, LDS_BYTES);

  k_emb <<<dim3(EMB_K),      dim3(EMB_C), 0,         stream>>>(emb, emb_bf, enorm, loss, ctr);
  k_main<<<dim3(NPIX / 256), dim3(512),   LDS_BYTES, stream>>>(x, emb, emb_bf, enorm,
                                                               out, loss, ctr);
}

// Round 12
// 156.874 us; speedup vs baseline: 1.0302x; 1.0302x over previous
//
#include <hip/hip_runtime.h>
#include <hip/hip_bf16.h>
#include <cstdint>
#include <cstddef>

#define EMB_K   1024
#define EMB_C   256
#define HWB     4096        // 64*64 per batch
#define NPIX    65536       // 16*4096

typedef __bf16 bf16x8 __attribute__((ext_vector_type(8)));
typedef float  f32x4  __attribute__((ext_vector_type(4)));

__device__ __forceinline__ unsigned short bf16bits(float v) {
  __hip_bfloat16 h = __float2bfloat16(v);
  return __builtin_bit_cast(unsigned short, h);
}

// ---- emb -> bf16 row-major + fp32 norms; zero loss ----
__global__ void k_emb(const float* __restrict__ emb, unsigned short* __restrict__ emb_bf,
                      float* __restrict__ enorm, float* __restrict__ loss) {
  int k = blockIdx.x;      // 0..1023
  int c = threadIdx.x;     // 0..255
  if (k == 0 && c == 0) *loss = 0.f;
  float v = emb[(size_t)k * EMB_C + c];
  emb_bf[(size_t)k * EMB_C + c] = bf16bits(v);
  float s = v * v;
  for (int m = 32; m; m >>= 1) s += __shfl_down(s, m, 64);
  __shared__ float red[4];
  int lane = c & 63, w = c >> 6;
  if (lane == 0) red[w] = s;
  __syncthreads();
  if (c == 0) enorm[k] = red[0] + red[1] + red[2] + red[3];
}

// ---- staging: 64 rows x 256c bf16 = 32KB, XOR-swizzled 16B chunks, glds ----
// 512-thread: 2048 chunks, 4 per thread (4 vmcnt units per stage)
__device__ __forceinline__ void stage64(const unsigned short* __restrict__ rows,
                                        unsigned char* buf, int t) {
#pragma unroll
  for (int j = 0; j < 4; ++j) {
    int d = j * 512 + t;             // linear dest chunk 0..2047
    int r = d >> 5;                  // row 0..63
    int slot = d & 31;
    int c16 = ((slot >> 3) << 3) | ((slot & 7) ^ (r & 7));
    const unsigned short* src = rows + (size_t)r * EMB_C + c16 * 8;
    __builtin_amdgcn_global_load_lds(
        (const __attribute__((address_space(1))) void*)src,
        (__attribute__((address_space(3))) void*)(buf + (unsigned)(j * 8192 + (t >> 6) * 1024)),
        16, 0, 0);
  }
}

// A-tile swizzle: key spreads BOTH stride-4-row prologue writes (nl=4*hwq+m)
// AND stride-1-row af reads.
__device__ __forceinline__ int posA(int cc, int nl) {
  return ((cc >> 3) << 3) | ((cc & 7) ^ ((nl ^ (nl >> 2)) & 7));
}

// ================= main kernel: transpose + GEMM + argmin + loss =================
// R10's proven body (77us fused) MINUS the output epilogue (~28us of pure data
// movement that ran at 2.5 TB/s because it was capped at this kernel's 8-wave
// occupancy). Keys exported to keys_g; the output gather/store moves to k_out
// at 32 waves/CU. 256 blocks x 512 thr, 1 block/CU.
// LDS: [0,128K) bufs 4x32KB (A-tile in bufs 2/3 during prologue) | cjl | keys | xn | red
#define LDS_BYTES 137280

__global__ __launch_bounds__(512) void
k_main(const float* __restrict__ x, const unsigned short* __restrict__ embbf,
       const float* __restrict__ enorm, unsigned* __restrict__ keys_g,
       float* __restrict__ loss) {
  extern __shared__ char smem[];
  unsigned char* Abase = (unsigned char*)smem + 65536;  // A-tile in bufs 2/3
  float*    cjl    = (float*)(smem + 131072);          // 1024 f32
  unsigned* keys_l = (unsigned*)(smem + 135168);       // 256 u32
  float*    xn_l   = (float*)(smem + 136192);          // 256 f32
  float*    red    = (float*)(smem + 137216);          // 16 f32

  int n0 = blockIdx.x * 256;
  int b  = n0 >> 12, hw0 = n0 & 4095;
  int t = threadIdx.x, w = t >> 6, lane = t & 63;
  int quad = lane >> 4, lr = lane & 15;
  int g  = w >> 1;       // n-group 0..3 (64 n)
  int h2 = w & 1;        // k-half (32 k of each 64k tile)

  // B(0)/B(1) staged early: latency hides under the whole prologue
  stage64(embbf,               (unsigned char*)smem,         t);
  stage64(embbf + 64 * EMB_C,  (unsigned char*)smem + 32768, t);

  if (t < 256) { keys_l[t] = 0u; xn_l[t] = 0.f; }
  for (int i = t; i < 1024; i += 512) cjl[i] = 0.375f - 0.5f * enorm[i];
  __syncthreads();

  // ---- prologue: x[c][hw] -> A-tile bf16 (2 passes of 128 n); float4 reads ----
  bf16x8 af[4][8];
#pragma unroll
  for (int p = 0; p < 2; ++p) {
    if (p) __syncthreads();            // pass-0 af reads done before rewrite
    {
      int hwq = t & 31;                // 4-hw quad -> n-local = hwq*4..+3
      int cg  = t >> 5;                // c-group 0..15 (16 c each)
      const float* xp = x + (size_t)b * (EMB_C * HWB) + hw0 + p * 128 + hwq * 4;
      float xn[4] = {0.f, 0.f, 0.f, 0.f};
      unsigned pk[4][8] = {};
#pragma unroll
      for (int j = 0; j < 16; ++j) {   // c = cg*16 + j
        f32x4 v = *(const f32x4*)(xp + (size_t)(cg * 16 + j) * HWB);  // 16B/lane
#pragma unroll
        for (int m = 0; m < 4; ++m) {
          xn[m] += v[m] * v[m];
          pk[m][j >> 1] |= (unsigned)bf16bits(v[m]) << ((j & 1) * 16);
        }
      }
#pragma unroll
      for (int m = 0; m < 4; ++m) {
        int nl = hwq * 4 + m;
        *(uint4*)(Abase + nl * 512 + posA(cg * 2,     nl) * 16) = *(const uint4*)&pk[m][0];
        *(uint4*)(Abase + nl * 512 + posA(cg * 2 + 1, nl) * 16) = *(const uint4*)&pk[m][4];
        atomicAdd(&xn_l[p * 128 + nl], xn[m]);
      }
    }
    __syncthreads();
    if ((g >> 1) == p) {               // n-groups {2p, 2p+1} load af this pass
#pragma unroll
      for (int i = 0; i < 4; ++i) {
        int rA = (g & 1) * 64 + i * 16 + lr;   // local row in this pass's 128
#pragma unroll
        for (int s = 0; s < 8; ++s) {
          int cc = s * 4 + quad;
          af[i][s] = *(const bf16x8*)(Abase + rA * 512 + posA(cc, rA) * 16);
        }
      }
    }
  }
  __syncthreads();   // af complete (drains vmcnt -> bufs 0/1 landed)

  // ---- K-loop: 16 tiles of 64 k; 4-buf rotation, 1 barrier + counted vmcnt ----
  unsigned best[4][4] = {};
  for (int kt = 0; kt < 16; ++kt) {
    if (kt < 14)
      stage64(embbf + (size_t)(kt + 2) * 64 * EMB_C,
              (unsigned char*)smem + (((kt + 2) & 3) << 15), t);
    // outstanding stages: kt,kt+1,kt+2 = 12 chunks -> wait oldest stage (4 each)
    if (kt < 14)       asm volatile("s_waitcnt vmcnt(8)" ::: "memory");
    else if (kt == 14) asm volatile("s_waitcnt vmcnt(4)" ::: "memory");
    else               asm volatile("s_waitcnt vmcnt(0)" ::: "memory");
    __builtin_amdgcn_s_barrier();              // all waves' stage(kt) landed
    __builtin_amdgcn_sched_barrier(0);         // no LDS-read hoist above
    const unsigned char* srcB = (const unsigned char*)smem + ((kt & 3) << 15);
    float cj[2]; unsigned kp[2];
#pragma unroll
    for (int j = 0; j < 2; ++j) {
      int k = kt * 64 + h2 * 32 + j * 16 + lr;
      cj[j] = cjl[k];
      kp[j] = 1023u - (unsigned)k;
    }
    f32x4 acc[4][2] = {};
#pragma unroll
    for (int s = 0; s < 8; ++s) {
      int cc = s * 4 + quad;
      int pos = ((cc >> 3) << 3) | ((cc & 7) ^ (lr & 7));   // B swizzle (rB&7==lr&7)
      bf16x8 bf[2];
#pragma unroll
      for (int j = 0; j < 2; ++j)
        bf[j] = *(const bf16x8*)(srcB + (h2 * 32 + j * 16 + lr) * 512 + pos * 16);
#pragma unroll
      for (int i = 0; i < 4; ++i)
#pragma unroll
        for (int j = 0; j < 2; ++j)
          acc[i][j] = __builtin_amdgcn_mfma_f32_16x16x32_bf16(af[i][s], bf[j], acc[i][j], 0, 0, 0);
    }
    // fold argmin keys: f = dot + 0.375 - 0.5||e||^2 in (0.04,0.71) -> positive
    // float u32-order-correct; low 10 mantissa bits carry (1023-k).
#pragma unroll
    for (int i = 0; i < 4; ++i)
#pragma unroll
      for (int j = 0; j < 2; ++j)
#pragma unroll
        for (int r = 0; r < 4; ++r) {
          float f = acc[i][j][r] + cj[j];
          unsigned key = (__float_as_uint(f) & 0xFFFFFC00u) | kp[j];
          best[i][r] = best[i][r] > key ? best[i][r] : key;
        }
  }
  __syncthreads();   // k-loop complete before keys_l atomics phase

  // ---- combine keys across k-lanes; k-halves via LDS atomicMax ----
#pragma unroll
  for (int i = 0; i < 4; ++i)
#pragma unroll
    for (int r = 0; r < 4; ++r) {
      unsigned v = best[i][r];
#pragma unroll
      for (int m = 1; m < 16; m <<= 1) {
        unsigned o = (unsigned)__shfl_xor((int)v, m, 64);
        v = v > o ? v : o;
      }
      if (lr == 0) atomicMax(&keys_l[g * 64 + i * 16 + quad * 4 + r], v);
    }
  __syncthreads();

  // ---- keys export + loss partial: d2 = ||x||^2 + 0.75 - 2*f_hat ----
  if (t < 256) {
    unsigned key = keys_l[t];
    keys_g[n0 + t] = key;
    float fh = __uint_as_float(key & 0xFFFFFC00u);
    float lsum = xn_l[t] + 0.75f - 2.0f * fh;
    for (int m = 32; m; m >>= 1) lsum += __shfl_down(lsum, m, 64);
    if (lane == 0) red[w] = lsum;
  }
  __syncthreads();
  if (t == 0)
    atomicAdd(loss, red[0] + red[1] + red[2] + red[3]);   // device-scope
}

// ================= output kernel: gather + transpose + store =================
// 2048 blocks x 256 thr, 16.6KB LDS -> 8 blocks/CU = 32 waves/CU (the
// occupancy the memory pipe needs; m13's 6.3TB/s copy runs at this TLP).
// Block e: n-tile nt=e>>1 (64 n), c-half cH=e&1 (128 c). Stride-65 LDS tile:
// conflict-free on both the c-scattered gather writes and the n-contiguous
// row reads. Stores: 256B/wave scalar rows, coalescer-merged, alignment-proof
// vs the out+1 offset. Loss finalize here (stream order: all k_main atomics
// complete before any k_out block starts).
__global__ __launch_bounds__(256) void
k_out(const float* __restrict__ emb, const unsigned* __restrict__ keys_g,
      const float* __restrict__ loss, float* __restrict__ out) {
  __shared__ float tile[64 * 65];            // 16.25 KB
  __shared__ int   idx_l[64];
  int e  = blockIdx.x;
  int nt = e >> 1, cH = e & 1;
  int n0 = nt * 64;
  int b  = n0 >> 12, hw0 = n0 & 4095;
  int t = threadIdx.x, w = t >> 6, lane = t & 63;
  if (e == 0 && t == 0)
    out[0] = 1.0625f * (*loss) / 16777216.0f;
  if (t < 64) idx_l[t] = 1023 - (int)(keys_g[n0 + t] & 1023u);
  __syncthreads();
  int nn = t >> 2, ch = t & 3;               // 4 threads per n
  const float* er = emb + (size_t)idx_l[nn] * EMB_C + cH * 128;
  float* ob = out + 1 + (size_t)b * (EMB_C * HWB) + (size_t)cH * 128 * HWB + hw0;
  for (int p = 0; p < 2; ++p) {              // 2 passes of 64 c
    if (p) __syncthreads();                  // pass-0 stores done before rewrite
#pragma unroll
    for (int q = 0; q < 4; ++q) {            // 4 lanes x 16B = 64B/line per (nn,q)
      f32x4 v = *(const f32x4*)(er + p * 64 + q * 16 + ch * 4);
#pragma unroll
      for (int m = 0; m < 4; ++m)
        tile[(q * 16 + ch * 4 + m) * 65 + nn] = v[m];
    }
    __syncthreads();
#pragma unroll
    for (int cc = 0; cc < 16; ++cc) {        // wave w: c-rows w*16..w*16+15
      int cl = w * 16 + cc;
      ob[(size_t)(p * 64 + cl) * HWB + lane] = tile[cl * 65 + lane];  // 256B/wave
    }
  }
}

extern "C" void kernel_launch(void* const* d_in, const int* in_sizes, int n_in,
                              void* d_out, int out_size, void* d_ws, size_t ws_size,
                              hipStream_t stream) {
  const float* x   = (const float*)d_in[0];   // [16,256,64,64]
  const float* emb = (const float*)d_in[1];   // [1024,256]
  float* out = (float*)d_out;                 // [1 + 16777216]
  char*  ws  = (char*)d_ws;

  unsigned short* emb_bf = (unsigned short*)ws;                 // 512 KB
  float*          enorm  = (float*)(ws + 524288);               // 4 KB
  float*          loss   = (float*)(ws + 528384);               // 4 B
  unsigned*       keys_g = (unsigned*)(ws + 532480);            // 256 KB

  hipFuncSetAttribute((const void*)k_main,
                      hipFuncAttributeMaxDynamicSharedMemorySize, LDS_BYTES);

  k_emb <<<dim3(EMB_K),      dim3(EMB_C), 0,         stream>>>(emb, emb_bf, enorm, loss);
  k_main<<<dim3(NPIX / 256), dim3(512),   LDS_BYTES, stream>>>(x, emb_bf, enorm,
                                                               keys_g, loss);
  k_out <<<dim3(NPIX / 32),  dim3(256),   0,         stream>>>(emb, keys_g, loss, out);
}